// Round 22
// baseline (430.312 us; speedup 1.0000x reference)
//
#include <hip/hip_runtime.h>
#include <cmath>

// ---- problem dims (fixed per reference) ----
#define YCH 8        // y_channels
#define NTR 16       // trials
#define LLEN 4096    // trial length
#define CK  16       // kernels per channel
#define KS  64       // kernel size
#define ENC 4033     // LLEN - KS + 1
#define NP  128      // YCH*NTR independent problems
#define INV_LIP 0.1f     // 1/10
#define THRESH 0.01f     // LAM/LIP = 0.1/10

#define XW4 272          // f4 slots per 1088-float window
#define XP4 289          // padded pitch (SW(271)=287 < 289)
// f4-slot swizzle: +1 pad slot per 16 -> breaks the 8-way bank conflict of
// the 16B lane stride (proven r12: 650->491us)
#define SW(s) ((s) + ((s) >> 4))

typedef float vfloat4 __attribute__((ext_vector_type(4)));

// volatile 16B LDS load (fallback path only)
__device__ __forceinline__ vfloat4 ldvol(const vfloat4* p) {
    return *(const volatile vfloat4*)p;
}
// plain 16B LDS load (r21-proven: no demotion with named-reg windows, and
// the backend batches lgkmcnt waits -> loads pipeline; volatile serialized)
__device__ __forceinline__ vfloat4 ldreg(const vfloat4* p) {
    return *p;
}

// component by compile-time-constant index (folds; no alloca)
#define C4(v, c) ((c) == 0 ? (v).x : (c) == 1 ? (v).y : (c) == 2 ? (v).z : (v).w)
// 20-float rolling window w0..w4, f in [0,19]
#define GW5(f) ((f) < 4  ? C4(w0, (f))      : \
                (f) < 8  ? C4(w1, (f) - 4)  : \
                (f) < 12 ? C4(w2, (f) - 8)  : \
                (f) < 16 ? C4(w3, (f) - 12) : C4(w4, (f) - 16))

// plain A load over [gi4, gi4+3], zero outside [0, ENC)
__device__ __forceinline__ float4 loadA4(const float* __restrict__ A,
                                         size_t coff, int gi4)
{
    if (gi4 >= 0 && gi4 + 3 < ENC) return *(const float4*)(A + coff + gi4);
    float r[4];
    #pragma unroll
    for (int j = 0; j < 4; ++j) {
        int gi = gi4 + j;
        r[j] = (gi >= 0 && gi < ENC) ? A[coff + gi] : 0.f;
    }
    return make_float4(r[0], r[1], r[2], r[3]);
}

// =====================================================================
// synth_quad: S[q][p][t] = sum_{c in quad q, k} A[p,c,t-k]*H[ch,c,k]
// r22: r16 geometry (tile 1024, 256 thr, 4 out/thread, LDS 18.5KB ->
// 8 blocks/CU = 32 waves, grid (4,4,128)) + r21 PLAIN loads. The 8-out
// 36.9KB-LDS shape only reached 8 waves/CU (alloc-granularity rounding);
// this shape measured 47-57% occupancy in r12/r16.
//   identity (r11-verified): t=t0+4*tid+j, k=16kg+mm, group float 16-mm+j
//   over base slot (tid+12-4kg); roll: new w0..w3 = slots 8-4kg..11-4kg.
// =====================================================================
__global__ __launch_bounds__(256) void synth_quad(
    const float* __restrict__ H, const float* __restrict__ A,
    float* __restrict__ S)
{
    __shared__ __align__(16) float xs[4 * XP4 * 4];  // 18496 B (swizzled)
    __shared__ __align__(16) float hs[4 * KS];       //  1024 B
    const int tid = threadIdx.x;
    const int t0  = blockIdx.x * 1024;
    const int c0  = blockIdx.y * 4;
    const int p   = blockIdx.z;
    const int ch  = p >> 4;

    if (tid < 64)
        ((float4*)hs)[tid] = ((const float4*)(H + ((size_t)ch * CK + c0) * KS))[tid];

    const size_t pbase = (size_t)p * CK * ENC;
    // stage 4 channels x 272 f4 = 1088 f4 (4.25 per thread), swizzled slots
    #pragma unroll
    for (int s = 0; s < 5; ++s) {
        int l4 = tid + 256 * s;
        if (l4 < 4 * XW4) {
            int c   = l4 / XW4;
            int off = l4 - c * XW4;
            ((float4*)xs)[c * XP4 + SW(off)] =
                loadA4(A, pbase + (size_t)(c0 + c) * ENC, t0 - 64 + 4 * off);
        }
    }
    __syncthreads();

    float acc[4] = {0.f, 0.f, 0.f, 0.f};

    #pragma unroll
    for (int cc = 0; cc < 4; ++cc) {
        const vfloat4* xb = (const vfloat4*)xs + cc * XP4;
        const float4*  hc = (const float4*)(hs + cc * KS);

        vfloat4 w0 = ldreg(xb + SW(tid + 12));
        vfloat4 w1 = ldreg(xb + SW(tid + 13));
        vfloat4 w2 = ldreg(xb + SW(tid + 14));
        vfloat4 w3 = ldreg(xb + SW(tid + 15));
        vfloat4 w4 = ldreg(xb + SW(tid + 16));
        #pragma unroll
        for (int kg = 0; kg < 4; ++kg) {
            const float4 h0 = hc[4*kg],   h1 = hc[4*kg+1];
            const float4 h2 = hc[4*kg+2], h3 = hc[4*kg+3];
            #pragma unroll
            for (int mm = 0; mm < 16; ++mm) {       // tap k = 16kg+mm
                const float4 hv = (mm < 4 ? h0 : mm < 8 ? h1 : mm < 12 ? h2 : h3);
                const float hm = C4(hv, mm & 3);
                #pragma unroll
                for (int j = 0; j < 4; ++j)
                    acc[j] = fmaf(GW5(16 - mm + j), hm, acc[j]);
            }
            if (kg < 3) {   // roll window down 4 slots; old w0 becomes w4
                w4 = w0;
                w0 = ldreg(xb + SW(tid + 8  - 4 * kg));
                w1 = ldreg(xb + SW(tid + 9  - 4 * kg));
                w2 = ldreg(xb + SW(tid + 10 - 4 * kg));
                w3 = ldreg(xb + SW(tid + 11 - 4 * kg));
            }
        }
    }

    const int t = t0 + 4 * tid;
    *(float4*)(S + ((size_t)blockIdx.y * NP + p) * LLEN + t) =
        make_float4(acc[0], acc[1], acc[2], acc[3]);
}

// =====================================================================
// synth_half: fallback (8 ch/block, 4-out rolling GW5) -- used only if
// the workspace cannot hold quarter-S arrays.
// =====================================================================
__global__ __launch_bounds__(256) void synth_half(
    const float* __restrict__ H, const float* __restrict__ A,
    float* __restrict__ S)
{
    __shared__ __align__(16) float xs[8 * XP4 * 4];
    __shared__ __align__(16) float hs[8 * KS];
    const int tid = threadIdx.x;
    const int t0  = blockIdx.x * 1024;
    const int c0  = blockIdx.y * 8;
    const int p   = blockIdx.z;
    const int ch  = p >> 4;

    if (tid < 128)
        ((float4*)hs)[tid] = ((const float4*)(H + ((size_t)ch * CK + c0) * KS))[tid];

    const size_t pbase = (size_t)p * CK * ENC;
    #pragma unroll
    for (int s = 0; s < 9; ++s) {
        int l4 = tid + 256 * s;
        if (l4 < 8 * XW4) {
            int c   = l4 / XW4;
            int off = l4 - c * XW4;
            ((float4*)xs)[c * XP4 + SW(off)] =
                loadA4(A, pbase + (size_t)(c0 + c) * ENC, t0 - 64 + 4 * off);
        }
    }
    __syncthreads();

    float acc[4] = {0.f, 0.f, 0.f, 0.f};

    #pragma unroll
    for (int cc = 0; cc < 8; ++cc) {
        const vfloat4* xb = (const vfloat4*)xs + cc * XP4;
        const float4*  hc = (const float4*)(hs + cc * KS);

        vfloat4 w0 = ldreg(xb + SW(tid + 12));
        vfloat4 w1 = ldreg(xb + SW(tid + 13));
        vfloat4 w2 = ldreg(xb + SW(tid + 14));
        vfloat4 w3 = ldreg(xb + SW(tid + 15));
        vfloat4 w4 = ldreg(xb + SW(tid + 16));
        #pragma unroll
        for (int kg = 0; kg < 4; ++kg) {
            const float4 h0 = hc[4*kg],   h1 = hc[4*kg+1];
            const float4 h2 = hc[4*kg+2], h3 = hc[4*kg+3];
            #pragma unroll
            for (int mm = 0; mm < 16; ++mm) {
                const float4 hv = (mm < 4 ? h0 : mm < 8 ? h1 : mm < 12 ? h2 : h3);
                const float hm = C4(hv, mm & 3);
                #pragma unroll
                for (int j = 0; j < 4; ++j)
                    acc[j] = fmaf(GW5(16 - mm + j), hm, acc[j]);
            }
            if (kg < 3) {
                w4 = w0;
                w0 = ldreg(xb + SW(tid + 8  - 4 * kg));
                w1 = ldreg(xb + SW(tid + 9  - 4 * kg));
                w2 = ldreg(xb + SW(tid + 10 - 4 * kg));
                w3 = ldreg(xb + SW(tid + 11 - 4 * kg));
            }
        }
    }

    const int t = t0 + 4 * tid;
    *(float4*)(S + ((size_t)blockIdx.y * NP + p) * LLEN + t) =
        make_float4(acc[0], acc[1], acc[2], acc[3]);
}

// =====================================================================
// fista_quad<NQ>: r12 body; staging recombines NQ S-streams per generation:
//   rs = y - c1*sum_q Scur[q] + c2*sum_q Sprev[q]; c1 = 1+gamma, c2 = gamma
//   g[c,i] = sum_k rs[i+k]*H[ch,c,k];  x_new = relu(B + g/LIP - thr)
// =====================================================================
template<int NQ>
__global__ __launch_bounds__(256) void fista_quad(
    const float* __restrict__ y,
    const float* __restrict__ Scur, const float* __restrict__ Sprev,
    const float* __restrict__ H,
    const float* __restrict__ Acur, const float* __restrict__ Aprev,
    float gamma, int first, int two, float c1, float c2,
    float* __restrict__ Anext)
{
    __shared__ __align__(16) float rs[XW4 * 4];
    __shared__ __align__(16) float hs[4 * KS];
    const int tid = threadIdx.x;
    const int i0  = blockIdx.x * 1024;
    const int c0  = blockIdx.y * 4;
    const int p   = blockIdx.z;
    const int n = p & 15, ch = p >> 4;

    if (tid < 64)
        ((float4*)hs)[tid] = ((const float4*)(H + ((size_t)ch * CK + c0) * KS))[tid];

    const float* ybase = y + ((size_t)n * YCH + ch) * LLEN;
    #pragma unroll
    for (int s = 0; s < 2; ++s) {
        int l4 = tid + 256 * s;
        if (l4 < XW4) {
            int gi4 = i0 + 4 * l4;
            float4 v;
            if (gi4 + 3 < LLEN) {
                v = *(const float4*)(ybase + gi4);
                if (!first) {
                    float sx = 0.f, sy = 0.f, sz = 0.f, sw = 0.f;
                    #pragma unroll
                    for (int q = 0; q < NQ; ++q) {
                        float4 a = *(const float4*)(Scur + ((size_t)q * NP + p) * LLEN + gi4);
                        sx += a.x; sy += a.y; sz += a.z; sw += a.w;
                    }
                    v.x -= c1 * sx; v.y -= c1 * sy; v.z -= c1 * sz; v.w -= c1 * sw;
                    if (two) {
                        sx = sy = sz = sw = 0.f;
                        #pragma unroll
                        for (int q = 0; q < NQ; ++q) {
                            float4 a = *(const float4*)(Sprev + ((size_t)q * NP + p) * LLEN + gi4);
                            sx += a.x; sy += a.y; sz += a.z; sw += a.w;
                        }
                        v.x += c2 * sx; v.y += c2 * sy; v.z += c2 * sz; v.w += c2 * sw;
                    }
                }
            } else {
                float r[4];
                #pragma unroll
                for (int j = 0; j < 4; ++j) {
                    int gi = gi4 + j;
                    if (gi < LLEN) {
                        float t = ybase[gi];
                        if (!first) {
                            float sc = 0.f;
                            #pragma unroll
                            for (int q = 0; q < NQ; ++q)
                                sc += Scur[((size_t)q * NP + p) * LLEN + gi];
                            t -= c1 * sc;
                            if (two) {
                                float sp = 0.f;
                                #pragma unroll
                                for (int q = 0; q < NQ; ++q)
                                    sp += Sprev[((size_t)q * NP + p) * LLEN + gi];
                                t += c2 * sp;
                            }
                        }
                        r[j] = t;
                    } else r[j] = 0.f;
                }
                v = make_float4(r[0], r[1], r[2], r[3]);
            }
            ((float4*)rs)[l4] = v;
        }
    }
    __syncthreads();

    // hoisted register window rs[4*tid .. 4*tid+67], shared by 4 channels
    float wf[68];
    const float4* rr = (const float4*)rs + tid;
    #pragma unroll
    for (int q = 0; q < 17; ++q) {
        float4 t4 = rr[q];
        wf[4*q] = t4.x; wf[4*q+1] = t4.y; wf[4*q+2] = t4.z; wf[4*q+3] = t4.w;
    }

    const int i = i0 + 4 * tid;
    const size_t pb = (size_t)p * CK * ENC;
    const bool vec = (i + 3 < ENC);

    float4 a0 = make_float4(0,0,0,0), p0 = make_float4(0,0,0,0);
    if (!first && vec) {
        a0 = *(const float4*)(Acur  + pb + (size_t)c0 * ENC + i);
        p0 = *(const float4*)(Aprev + pb + (size_t)c0 * ENC + i);
    }

    for (int cc = 0; cc < 4; ++cc) {
        float4 a1 = make_float4(0,0,0,0), p1 = make_float4(0,0,0,0);
        if (!first && vec && cc < 3) {
            a1 = *(const float4*)(Acur  + pb + (size_t)(c0 + cc + 1) * ENC + i);
            p1 = *(const float4*)(Aprev + pb + (size_t)(c0 + cc + 1) * ENC + i);
        }

        float acc[4] = {0.f, 0.f, 0.f, 0.f};
        const float4* hc = (const float4*)(hs + cc * KS);
        #pragma unroll
        for (int g = 0; g < 16; ++g) {
            float4 h4 = hc[g];
            float hh[4] = {h4.x, h4.y, h4.z, h4.w};
            #pragma unroll
            for (int m = 0; m < 4; ++m) {
                const int k = 4 * g + m;
                #pragma unroll
                for (int j = 0; j < 4; ++j)
                    acc[j] = fmaf(wf[k + j], hh[m], acc[j]);
            }
        }

        const size_t idx = pb + (size_t)(c0 + cc) * ENC + i;
        if (vec) {
            float B[4] = {0.f, 0.f, 0.f, 0.f};
            if (!first) {
                float av[4] = {a0.x, a0.y, a0.z, a0.w};
                float pv[4] = {p0.x, p0.y, p0.z, p0.w};
                #pragma unroll
                for (int j = 0; j < 4; ++j) B[j] = fmaf(gamma, av[j] - pv[j], av[j]);
            }
            float4 o;
            o.x = fmaxf(fmaf(acc[0], INV_LIP, B[0]) - THRESH, 0.f);
            o.y = fmaxf(fmaf(acc[1], INV_LIP, B[1]) - THRESH, 0.f);
            o.z = fmaxf(fmaf(acc[2], INV_LIP, B[2]) - THRESH, 0.f);
            o.w = fmaxf(fmaf(acc[3], INV_LIP, B[3]) - THRESH, 0.f);
            *(float4*)(Anext + idx) = o;
        } else if (i < ENC) {
            #pragma unroll
            for (int j = 0; j < 4; ++j) {
                if (i + j < ENC) {
                    float B = 0.f;
                    if (!first) {
                        float a = Acur[idx + j], pp = Aprev[idx + j];
                        B = fmaf(gamma, a - pp, a);
                    }
                    Anext[idx + j] = fmaxf(fmaf(acc[j], INV_LIP, B) - THRESH, 0.f);
                }
            }
        }
        a0 = a1; p0 = p1;
    }
}

// =====================================================================
extern "C" void kernel_launch(void* const* d_in, const int* in_sizes, int n_in,
                              void* d_out, int out_size, void* d_ws, size_t ws_size,
                              hipStream_t stream)
{
    const float* y = (const float*)d_in[0];   // [NTR, YCH, LLEN]
    const float* H = (const float*)d_in[1];   // [YCH, CK, 1, KS]
    const size_t XSZ = (size_t)NP * CK * ENC; // 8,259,584 floats
    const size_t RSZ = (size_t)NP * LLEN;     //   524,288 floats

    float* bufA = (float*)d_ws;               // A_t for even t
    float* bufB = (float*)d_out;              // A_t for odd t (A9 -> d_out)
    float* Sgen = bufA + XSZ;                 // 2 gens x [NQ][NP][LLEN]

    // quarters need XSZ + 8*RSZ floats of workspace; else fall back to halves
    const bool quarters = ws_size >= (XSZ + 8 * RSZ) * sizeof(float);
    const int NQ = quarters ? 4 : 2;

    double s[11]; s[0] = 1.0;
    for (int t = 1; t <= 10; ++t) s[t] = 0.5 * (1.0 + sqrt(1.0 + 4.0 * s[t-1] * s[t-1]));

    dim3 gSq(4, 4, NP), gSh(4, 2, NP), gF(4, 4, NP);

    for (int t = 0; t < 10; ++t) {
        float gamma = (t == 0) ? 0.f : (float)((s[t-1] - 1.0) / s[t]);
        float* Anext       = (t & 1) ? bufB : bufA;
        const float* Acur  = (t & 1) ? bufA : bufB;              // A_{t-1}
        const float* Aprev = (t <= 1) ? Acur                     // gamma==0, unused
                                      : ((t & 1) ? bufB : bufA); // A_{t-2}
        if (t == 0) {
            if (quarters)
                fista_quad<4><<<gF, 256, 0, stream>>>(y, Sgen, Sgen, H, bufA, bufA,
                                                      0.f, 1, 0, 0.f, 0.f, bufA);
            else
                fista_quad<2><<<gF, 256, 0, stream>>>(y, Sgen, Sgen, H, bufA, bufA,
                                                      0.f, 1, 0, 0.f, 0.f, bufA);
        } else {
            float* Sc = Sgen + (size_t)((t - 1) & 1) * NQ * RSZ;  // S_{t-1}
            float* Sp = Sgen + (size_t)(t & 1) * NQ * RSZ;        // S_{t-2} (t>=2)
            if (quarters) {
                synth_quad<<<gSq, 256, 0, stream>>>(H, Acur, Sc);
                fista_quad<4><<<gF, 256, 0, stream>>>(y, Sc, Sp, H, Acur, Aprev,
                                                      gamma, 0, (t >= 2) ? 1 : 0,
                                                      1.f + gamma, gamma, Anext);
            } else {
                synth_half<<<gSh, 256, 0, stream>>>(H, Acur, Sc);
                fista_quad<2><<<gF, 256, 0, stream>>>(y, Sc, Sp, H, Acur, Aprev,
                                                      gamma, 0, (t >= 2) ? 1 : 0,
                                                      1.f + gamma, gamma, Anext);
            }
        }
    }
}

// Round 23
// 425.266 us; speedup vs baseline: 1.0119x; 1.0119x over previous
//
#include <hip/hip_runtime.h>
#include <cmath>

// ---- problem dims (fixed per reference) ----
#define YCH 8        // y_channels
#define NTR 16       // trials
#define LLEN 4096    // trial length
#define CK  16       // kernels per channel
#define KS  64       // kernel size
#define ENC 4033     // LLEN - KS + 1
#define NP  128      // YCH*NTR independent problems
#define INV_LIP 0.1f     // 1/10
#define THRESH 0.01f     // LAM/LIP = 0.1/10

#define XW4 272          // f4 slots per 1088-float window
#define XP4 289          // padded pitch (SW(271)=287 < 289)
// f4-slot swizzle: +1 pad slot per 16 -> breaks the 8-way bank conflict of
// the 16B lane stride (proven r12: 650->491us)
#define SW(s) ((s) + ((s) >> 4))

typedef float vfloat4 __attribute__((ext_vector_type(4)));

// plain 16B LDS load (r21-proven: no demotion with named-reg windows; the
// backend batches lgkmcnt waits so loads pipeline -- volatile serialized)
__device__ __forceinline__ vfloat4 ldreg(const vfloat4* p) {
    return *p;
}

// component by compile-time-constant index (folds; no alloca)
#define C4(v, c) ((c) == 0 ? (v).x : (c) == 1 ? (v).y : (c) == 2 ? (v).z : (v).w)
// 20-float rolling window w0..w4, f in [0,19]  (fallback synth)
#define GW5(f) ((f) < 4  ? C4(w0, (f))      : \
                (f) < 8  ? C4(w1, (f) - 4)  : \
                (f) < 12 ? C4(w2, (f) - 8)  : \
                (f) < 16 ? C4(w3, (f) - 12) : C4(w4, (f) - 16))
// 24-float rolling window u0..u5, f in [0,23]  (8-out synth)
#define GW6(f) ((f) < 4  ? C4(u0, (f))      : \
                (f) < 8  ? C4(u1, (f) - 4)  : \
                (f) < 12 ? C4(u2, (f) - 8)  : \
                (f) < 16 ? C4(u3, (f) - 12) : \
                (f) < 20 ? C4(u4, (f) - 16) : C4(u5, (f) - 20))

// plain A load over [gi4, gi4+3], zero outside [0, ENC)
__device__ __forceinline__ float4 loadA4(const float* __restrict__ A,
                                         size_t coff, int gi4)
{
    if (gi4 >= 0 && gi4 + 3 < ENC) return *(const float4*)(A + coff + gi4);
    float r[4];
    #pragma unroll
    for (int j = 0; j < 4; ++j) {
        int gi = gi4 + j;
        r[j] = (gi >= 0 && gi < ENC) ? A[coff + gi] : 0.f;
    }
    return make_float4(r[0], r[1], r[2], r[3]);
}

// =====================================================================
// synth_quad: S[q][p][t] = sum_{c in quad q, k} A[p,c,t-k]*H[ch,c,k]
// r23: 8-out OP-EFFICIENCY at 4-out OCCUPANCY. 128 thr x tile 1024 x
// 8 out/thread -> LDS 18.5KB (the footprint that measures 47-57% occ,
// 8 blocks/CU = 16 waves) with the halved-LDS-op profile (0.59M b128/
// dispatch vs 1.22M for 4-out). r21/r22 showed: 4-out = issue-bound at
// its 24us floor; 8-out = latency-bound at 8 waves. This combines both.
//   identity (r21-verified): out t=t0+8*tid+j needs local[8*tid+64+j-k];
//   k=16kg+mm; base slot 2*tid+12-4kg => group float 16+j-mm in [1,23];
//   roll: new u4,u5 = old u0,u1; fresh u0..u3 = slots 8-4kg..11-4kg.
// =====================================================================
__global__ __launch_bounds__(128) void synth_quad(
    const float* __restrict__ H, const float* __restrict__ A,
    float* __restrict__ S)
{
    __shared__ __align__(16) float xs[4 * XP4 * 4];  // 18496 B (swizzled)
    __shared__ __align__(16) float hs[4 * KS];       //  1024 B
    const int tid = threadIdx.x;
    const int t0  = blockIdx.x * 1024;
    const int c0  = blockIdx.y * 4;
    const int p   = blockIdx.z;
    const int ch  = p >> 4;

    if (tid < 64)
        ((float4*)hs)[tid] = ((const float4*)(H + ((size_t)ch * CK + c0) * KS))[tid];

    const size_t pbase = (size_t)p * CK * ENC;
    // stage 4 channels x 272 f4 = 1088 f4 (8.5 per thread), swizzled slots
    #pragma unroll
    for (int s = 0; s < 9; ++s) {
        int l4 = tid + 128 * s;
        if (l4 < 4 * XW4) {
            int c   = l4 / XW4;
            int off = l4 - c * XW4;
            ((float4*)xs)[c * XP4 + SW(off)] =
                loadA4(A, pbase + (size_t)(c0 + c) * ENC, t0 - 64 + 4 * off);
        }
    }
    __syncthreads();

    float acc[8] = {0.f,0.f,0.f,0.f,0.f,0.f,0.f,0.f};

    #pragma unroll
    for (int cc = 0; cc < 4; ++cc) {
        const vfloat4* xb = (const vfloat4*)xs + cc * XP4;
        const float4*  hc = (const float4*)(hs + cc * KS);

        vfloat4 u0 = ldreg(xb + SW(2 * tid + 12));
        vfloat4 u1 = ldreg(xb + SW(2 * tid + 13));
        vfloat4 u2 = ldreg(xb + SW(2 * tid + 14));
        vfloat4 u3 = ldreg(xb + SW(2 * tid + 15));
        vfloat4 u4 = ldreg(xb + SW(2 * tid + 16));
        vfloat4 u5 = ldreg(xb + SW(2 * tid + 17));
        #pragma unroll
        for (int kg = 0; kg < 4; ++kg) {
            const float4 h0 = hc[4*kg],   h1 = hc[4*kg+1];
            const float4 h2 = hc[4*kg+2], h3 = hc[4*kg+3];
            #pragma unroll
            for (int mm = 0; mm < 16; ++mm) {       // tap k = 16kg+mm
                const float4 hv = (mm < 4 ? h0 : mm < 8 ? h1 : mm < 12 ? h2 : h3);
                const float hm = C4(hv, mm & 3);
                #pragma unroll
                for (int j = 0; j < 8; ++j)
                    acc[j] = fmaf(GW6(16 + j - mm), hm, acc[j]);
            }
            if (kg < 3) {   // roll window down 4 slots
                u4 = u0; u5 = u1;
                u0 = ldreg(xb + SW(2 * tid + 8  - 4 * kg));
                u1 = ldreg(xb + SW(2 * tid + 9  - 4 * kg));
                u2 = ldreg(xb + SW(2 * tid + 10 - 4 * kg));
                u3 = ldreg(xb + SW(2 * tid + 11 - 4 * kg));
            }
        }
    }

    const int t = t0 + 8 * tid;
    float* dst = S + ((size_t)blockIdx.y * NP + p) * LLEN + t;
    *(float4*)(dst)     = make_float4(acc[0], acc[1], acc[2], acc[3]);
    *(float4*)(dst + 4) = make_float4(acc[4], acc[5], acc[6], acc[7]);
}

// =====================================================================
// synth_half: fallback (8 ch/block, 4-out rolling GW5) -- used only if
// the workspace cannot hold quarter-S arrays.
// =====================================================================
__global__ __launch_bounds__(256) void synth_half(
    const float* __restrict__ H, const float* __restrict__ A,
    float* __restrict__ S)
{
    __shared__ __align__(16) float xs[8 * XP4 * 4];
    __shared__ __align__(16) float hs[8 * KS];
    const int tid = threadIdx.x;
    const int t0  = blockIdx.x * 1024;
    const int c0  = blockIdx.y * 8;
    const int p   = blockIdx.z;
    const int ch  = p >> 4;

    if (tid < 128)
        ((float4*)hs)[tid] = ((const float4*)(H + ((size_t)ch * CK + c0) * KS))[tid];

    const size_t pbase = (size_t)p * CK * ENC;
    #pragma unroll
    for (int s = 0; s < 9; ++s) {
        int l4 = tid + 256 * s;
        if (l4 < 8 * XW4) {
            int c   = l4 / XW4;
            int off = l4 - c * XW4;
            ((float4*)xs)[c * XP4 + SW(off)] =
                loadA4(A, pbase + (size_t)(c0 + c) * ENC, t0 - 64 + 4 * off);
        }
    }
    __syncthreads();

    float acc[4] = {0.f, 0.f, 0.f, 0.f};

    #pragma unroll
    for (int cc = 0; cc < 8; ++cc) {
        const vfloat4* xb = (const vfloat4*)xs + cc * XP4;
        const float4*  hc = (const float4*)(hs + cc * KS);

        vfloat4 w0 = ldreg(xb + SW(tid + 12));
        vfloat4 w1 = ldreg(xb + SW(tid + 13));
        vfloat4 w2 = ldreg(xb + SW(tid + 14));
        vfloat4 w3 = ldreg(xb + SW(tid + 15));
        vfloat4 w4 = ldreg(xb + SW(tid + 16));
        #pragma unroll
        for (int kg = 0; kg < 4; ++kg) {
            const float4 h0 = hc[4*kg],   h1 = hc[4*kg+1];
            const float4 h2 = hc[4*kg+2], h3 = hc[4*kg+3];
            #pragma unroll
            for (int mm = 0; mm < 16; ++mm) {
                const float4 hv = (mm < 4 ? h0 : mm < 8 ? h1 : mm < 12 ? h2 : h3);
                const float hm = C4(hv, mm & 3);
                #pragma unroll
                for (int j = 0; j < 4; ++j)
                    acc[j] = fmaf(GW5(16 - mm + j), hm, acc[j]);
            }
            if (kg < 3) {
                w4 = w0;
                w0 = ldreg(xb + SW(tid + 8  - 4 * kg));
                w1 = ldreg(xb + SW(tid + 9  - 4 * kg));
                w2 = ldreg(xb + SW(tid + 10 - 4 * kg));
                w3 = ldreg(xb + SW(tid + 11 - 4 * kg));
            }
        }
    }

    const int t = t0 + 4 * tid;
    *(float4*)(S + ((size_t)blockIdx.y * NP + p) * LLEN + t) =
        make_float4(acc[0], acc[1], acc[2], acc[3]);
}

// =====================================================================
// fista_quad<NQ>: r12 body; staging recombines NQ S-streams per generation:
//   rs = y - c1*sum_q Scur[q] + c2*sum_q Sprev[q]; c1 = 1+gamma, c2 = gamma
//   g[c,i] = sum_k rs[i+k]*H[ch,c,k];  x_new = relu(B + g/LIP - thr)
// =====================================================================
template<int NQ>
__global__ __launch_bounds__(256) void fista_quad(
    const float* __restrict__ y,
    const float* __restrict__ Scur, const float* __restrict__ Sprev,
    const float* __restrict__ H,
    const float* __restrict__ Acur, const float* __restrict__ Aprev,
    float gamma, int first, int two, float c1, float c2,
    float* __restrict__ Anext)
{
    __shared__ __align__(16) float rs[XW4 * 4];
    __shared__ __align__(16) float hs[4 * KS];
    const int tid = threadIdx.x;
    const int i0  = blockIdx.x * 1024;
    const int c0  = blockIdx.y * 4;
    const int p   = blockIdx.z;
    const int n = p & 15, ch = p >> 4;

    if (tid < 64)
        ((float4*)hs)[tid] = ((const float4*)(H + ((size_t)ch * CK + c0) * KS))[tid];

    const float* ybase = y + ((size_t)n * YCH + ch) * LLEN;
    #pragma unroll
    for (int s = 0; s < 2; ++s) {
        int l4 = tid + 256 * s;
        if (l4 < XW4) {
            int gi4 = i0 + 4 * l4;
            float4 v;
            if (gi4 + 3 < LLEN) {
                v = *(const float4*)(ybase + gi4);
                if (!first) {
                    float sx = 0.f, sy = 0.f, sz = 0.f, sw = 0.f;
                    #pragma unroll
                    for (int q = 0; q < NQ; ++q) {
                        float4 a = *(const float4*)(Scur + ((size_t)q * NP + p) * LLEN + gi4);
                        sx += a.x; sy += a.y; sz += a.z; sw += a.w;
                    }
                    v.x -= c1 * sx; v.y -= c1 * sy; v.z -= c1 * sz; v.w -= c1 * sw;
                    if (two) {
                        sx = sy = sz = sw = 0.f;
                        #pragma unroll
                        for (int q = 0; q < NQ; ++q) {
                            float4 a = *(const float4*)(Sprev + ((size_t)q * NP + p) * LLEN + gi4);
                            sx += a.x; sy += a.y; sz += a.z; sw += a.w;
                        }
                        v.x += c2 * sx; v.y += c2 * sy; v.z += c2 * sz; v.w += c2 * sw;
                    }
                }
            } else {
                float r[4];
                #pragma unroll
                for (int j = 0; j < 4; ++j) {
                    int gi = gi4 + j;
                    if (gi < LLEN) {
                        float t = ybase[gi];
                        if (!first) {
                            float sc = 0.f;
                            #pragma unroll
                            for (int q = 0; q < NQ; ++q)
                                sc += Scur[((size_t)q * NP + p) * LLEN + gi];
                            t -= c1 * sc;
                            if (two) {
                                float sp = 0.f;
                                #pragma unroll
                                for (int q = 0; q < NQ; ++q)
                                    sp += Sprev[((size_t)q * NP + p) * LLEN + gi];
                                t += c2 * sp;
                            }
                        }
                        r[j] = t;
                    } else r[j] = 0.f;
                }
                v = make_float4(r[0], r[1], r[2], r[3]);
            }
            ((float4*)rs)[l4] = v;
        }
    }
    __syncthreads();

    // hoisted register window rs[4*tid .. 4*tid+67], shared by 4 channels
    float wf[68];
    const float4* rr = (const float4*)rs + tid;
    #pragma unroll
    for (int q = 0; q < 17; ++q) {
        float4 t4 = rr[q];
        wf[4*q] = t4.x; wf[4*q+1] = t4.y; wf[4*q+2] = t4.z; wf[4*q+3] = t4.w;
    }

    const int i = i0 + 4 * tid;
    const size_t pb = (size_t)p * CK * ENC;
    const bool vec = (i + 3 < ENC);

    float4 a0 = make_float4(0,0,0,0), p0 = make_float4(0,0,0,0);
    if (!first && vec) {
        a0 = *(const float4*)(Acur  + pb + (size_t)c0 * ENC + i);
        p0 = *(const float4*)(Aprev + pb + (size_t)c0 * ENC + i);
    }

    for (int cc = 0; cc < 4; ++cc) {
        float4 a1 = make_float4(0,0,0,0), p1 = make_float4(0,0,0,0);
        if (!first && vec && cc < 3) {
            a1 = *(const float4*)(Acur  + pb + (size_t)(c0 + cc + 1) * ENC + i);
            p1 = *(const float4*)(Aprev + pb + (size_t)(c0 + cc + 1) * ENC + i);
        }

        float acc[4] = {0.f, 0.f, 0.f, 0.f};
        const float4* hc = (const float4*)(hs + cc * KS);
        #pragma unroll
        for (int g = 0; g < 16; ++g) {
            float4 h4 = hc[g];
            float hh[4] = {h4.x, h4.y, h4.z, h4.w};
            #pragma unroll
            for (int m = 0; m < 4; ++m) {
                const int k = 4 * g + m;
                #pragma unroll
                for (int j = 0; j < 4; ++j)
                    acc[j] = fmaf(wf[k + j], hh[m], acc[j]);
            }
        }

        const size_t idx = pb + (size_t)(c0 + cc) * ENC + i;
        if (vec) {
            float B[4] = {0.f, 0.f, 0.f, 0.f};
            if (!first) {
                float av[4] = {a0.x, a0.y, a0.z, a0.w};
                float pv[4] = {p0.x, p0.y, p0.z, p0.w};
                #pragma unroll
                for (int j = 0; j < 4; ++j) B[j] = fmaf(gamma, av[j] - pv[j], av[j]);
            }
            float4 o;
            o.x = fmaxf(fmaf(acc[0], INV_LIP, B[0]) - THRESH, 0.f);
            o.y = fmaxf(fmaf(acc[1], INV_LIP, B[1]) - THRESH, 0.f);
            o.z = fmaxf(fmaf(acc[2], INV_LIP, B[2]) - THRESH, 0.f);
            o.w = fmaxf(fmaf(acc[3], INV_LIP, B[3]) - THRESH, 0.f);
            *(float4*)(Anext + idx) = o;
        } else if (i < ENC) {
            #pragma unroll
            for (int j = 0; j < 4; ++j) {
                if (i + j < ENC) {
                    float B = 0.f;
                    if (!first) {
                        float a = Acur[idx + j], pp = Aprev[idx + j];
                        B = fmaf(gamma, a - pp, a);
                    }
                    Anext[idx + j] = fmaxf(fmaf(acc[j], INV_LIP, B) - THRESH, 0.f);
                }
            }
        }
        a0 = a1; p0 = p1;
    }
}

// =====================================================================
extern "C" void kernel_launch(void* const* d_in, const int* in_sizes, int n_in,
                              void* d_out, int out_size, void* d_ws, size_t ws_size,
                              hipStream_t stream)
{
    const float* y = (const float*)d_in[0];   // [NTR, YCH, LLEN]
    const float* H = (const float*)d_in[1];   // [YCH, CK, 1, KS]
    const size_t XSZ = (size_t)NP * CK * ENC; // 8,259,584 floats
    const size_t RSZ = (size_t)NP * LLEN;     //   524,288 floats

    float* bufA = (float*)d_ws;               // A_t for even t
    float* bufB = (float*)d_out;              // A_t for odd t (A9 -> d_out)
    float* Sgen = bufA + XSZ;                 // 2 gens x [NQ][NP][LLEN]

    // quarters need XSZ + 8*RSZ floats of workspace; else fall back to halves
    const bool quarters = ws_size >= (XSZ + 8 * RSZ) * sizeof(float);
    const int NQ = quarters ? 4 : 2;

    double s[11]; s[0] = 1.0;
    for (int t = 1; t <= 10; ++t) s[t] = 0.5 * (1.0 + sqrt(1.0 + 4.0 * s[t-1] * s[t-1]));

    dim3 gSq(4, 4, NP), gSh(4, 2, NP), gF(4, 4, NP);

    for (int t = 0; t < 10; ++t) {
        float gamma = (t == 0) ? 0.f : (float)((s[t-1] - 1.0) / s[t]);
        float* Anext       = (t & 1) ? bufB : bufA;
        const float* Acur  = (t & 1) ? bufA : bufB;              // A_{t-1}
        const float* Aprev = (t <= 1) ? Acur                     // gamma==0, unused
                                      : ((t & 1) ? bufB : bufA); // A_{t-2}
        if (t == 0) {
            if (quarters)
                fista_quad<4><<<gF, 256, 0, stream>>>(y, Sgen, Sgen, H, bufA, bufA,
                                                      0.f, 1, 0, 0.f, 0.f, bufA);
            else
                fista_quad<2><<<gF, 256, 0, stream>>>(y, Sgen, Sgen, H, bufA, bufA,
                                                      0.f, 1, 0, 0.f, 0.f, bufA);
        } else {
            float* Sc = Sgen + (size_t)((t - 1) & 1) * NQ * RSZ;  // S_{t-1}
            float* Sp = Sgen + (size_t)(t & 1) * NQ * RSZ;        // S_{t-2} (t>=2)
            if (quarters) {
                synth_quad<<<gSq, 128, 0, stream>>>(H, Acur, Sc);
                fista_quad<4><<<gF, 256, 0, stream>>>(y, Sc, Sp, H, Acur, Aprev,
                                                      gamma, 0, (t >= 2) ? 1 : 0,
                                                      1.f + gamma, gamma, Anext);
            } else {
                synth_half<<<gSh, 256, 0, stream>>>(H, Acur, Sc);
                fista_quad<2><<<gF, 256, 0, stream>>>(y, Sc, Sp, H, Acur, Aprev,
                                                      gamma, 0, (t >= 2) ? 1 : 0,
                                                      1.f + gamma, gamma, Anext);
            }
        }
    }
}